// Round 12
// baseline (475.357 us; speedup 1.0000x reference)
//
#include <hip/hip_runtime.h>

#define HW 256
#define HWMASK 255
#define CH 128
#define BATCH 8
#define NK 4
#define STRIP 16           // rows per thread (wave = full 256-col row)
#define NIN (STRIP + 6)    // input rows touched per strip

typedef float f32x4 __attribute__((ext_vector_type(4)));

// ---------------- Kernel A1: partial sums of guidance ----------------
__global__ __launch_bounds__(256) void mean1_kernel(const float* __restrict__ guid,
                                                    float* __restrict__ partial) {
    int blk = blockIdx.x;
    const float4* p = (const float4*)(guid + (size_t)blk * 16384);
    float s = 0.f;
    for (int i = threadIdx.x; i < 4096; i += 256) {
        float4 v = p[i];
        s += (v.x + v.y) + (v.z + v.w);
    }
    for (int off = 32; off; off >>= 1) s += __shfl_down(s, off, 64);
    __shared__ float red[4];
    if ((threadIdx.x & 63) == 0) red[threadIdx.x >> 6] = s;
    __syncthreads();
    if (threadIdx.x == 0) partial[blk] = (red[0] + red[1]) + (red[2] + red[3]);
}

// ---------------- Kernel B: finalize means + MLP + softmax ----------------
__global__ __launch_bounds__(256) void mlp_kernel(const float* __restrict__ partial,
                                                  const float* __restrict__ w1,
                                                  const float* __restrict__ b1,
                                                  const float* __restrict__ w2,
                                                  const float* __restrict__ b2,
                                                  float* __restrict__ wt) {
    __shared__ float gs[BATCH * CH];
    __shared__ float h1[BATCH * 32];
    __shared__ float lg[BATCH * NK];
    int t = threadIdx.x;
    for (int i = t; i < BATCH * CH; i += 256) {
        float4 v = *(const float4*)(partial + i * 4);
        gs[i] = ((v.x + v.y) + (v.z + v.w)) * (1.0f / 65536.0f);
    }
    __syncthreads();
    {
        int b = t >> 5, j = t & 31;
        float acc = b1[j];
        #pragma unroll 4
        for (int c = 0; c < CH; ++c) acc += gs[b * CH + c] * w1[j * CH + c];
        h1[b * 32 + j] = fmaxf(acc, 0.f);
    }
    __syncthreads();
    if (t < BATCH * NK) {
        int b = t >> 2, k = t & 3;
        float acc = b2[k];
        #pragma unroll
        for (int j = 0; j < 32; ++j) acc += h1[b * 32 + j] * w2[k * 32 + j];
        lg[b * NK + k] = acc;
    }
    __syncthreads();
    if (t < BATCH) {
        int b = t;
        float m = lg[b * 4];
        for (int k = 1; k < 4; ++k) m = fmaxf(m, lg[b * 4 + k]);
        float e[4], s = 0.f;
        for (int k = 0; k < 4; ++k) { e[k] = expf(lg[b * 4 + k] - m); s += e[k]; }
        float inv = 1.0f / s;
        for (int k = 0; k < 4; ++k) wt[b * 4 + k] = e[k] * inv;
    }
}

// ---------------- Kernel C: dyn = blend of basis filters, stored FLIPPED ----------------
__global__ __launch_bounds__(256) void dyn_kernel(const float* __restrict__ wt,
                                                  const float* __restrict__ basis,
                                                  float* __restrict__ dynF) {
    int idx = blockIdx.x * 256 + threadIdx.x;
    if (idx >= BATCH * CH * 49) return;
    int ij = idx % 49;
    int bc = idx / 49;
    int c = bc % CH;
    int b = bc / CH;
    float acc = 0.f;
    #pragma unroll
    for (int k = 0; k < NK; ++k)
        acc += wt[b * NK + k] * basis[(k * CH + c) * 49 + ij];
    dynF[bc * 49 + (48 - ij)] = acc;
}

// ---------------- Kernel D: circular depthwise 7x7 conv, register sliding window ----
// No LDS, no barriers. Wave = 64 lanes x 4 cols = full 256-px row; strip = 16 rows
// (22 iterations -> guaranteed full unroll, pf indices compile-time).
// Depth-2 row prefetch = 6 loads in flight/wave; launch_bounds(256,8) pins
// VGPR<=64 -> 8 blocks/CU -> ~192 outstanding loads/CU to cover latency.
__global__ __launch_bounds__(256, 8) void conv_kernel(const float* __restrict__ x,
                                                      const float* __restrict__ dynF,
                                                      float* __restrict__ out) {
    int bc = blockIdx.x;                  // 0..1023 plane id
    const float* xp = x + (size_t)bc * (HW * HW);
    float* op = out + (size_t)bc * (HW * HW);
    int tid = threadIdx.x;
    int lane = tid & 63, ty = tid >> 6;
    int yb = blockIdx.y * (4 * STRIP) + ty * STRIP;

    // filter taps: block-uniform address -> scalar loads into SGPRs
    const float* df = dynF + bc * 49;
    float d[49];
    #pragma unroll
    for (int i = 0; i < 49; ++i) d[i] = df[i];

    // wrapped quad offsets: cols 4*lane-4 .. 4*lane+7 (window needs 4l-3..4l+6)
    int gx0 = (4 * lane - 4) & HWMASK;
    int gx1 = (4 * lane) & HWMASK;
    int gx2 = (4 * lane + 4) & HWMASK;

    // prologue: prefetch input rows 0,1 of the window
    float4 pf[2][3];
    #pragma unroll
    for (int k = 0; k < 2; ++k) {
        const float* rp = xp + (((yb + k - 3) & HWMASK) * HW);
        pf[k][0] = *(const float4*)(rp + gx0);
        pf[k][1] = *(const float4*)(rp + gx1);
        pf[k][2] = *(const float4*)(rp + gx2);
    }

    float acc[7][4] = {};
    #pragma unroll
    for (int i = 0; i < NIN; ++i) {
        float4 A = pf[i & 1][0], B = pf[i & 1][1], C = pf[i & 1][2];
        // issue prefetch of row i+2 into the slot we just consumed
        if (i + 2 < NIN) {
            const float* rp = xp + (((yb + i - 1) & HWMASK) * HW);
            pf[i & 1][0] = *(const float4*)(rp + gx0);
            pf[i & 1][1] = *(const float4*)(rp + gx1);
            pf[i & 1][2] = *(const float4*)(rp + gx2);
        }
        float v[12] = {A.x, A.y, A.z, A.w, B.x, B.y, B.z, B.w, C.x, C.y, C.z, C.w};
        #pragma unroll
        for (int ii = 0; ii < 7; ++ii) {
            int o = i - ii;                       // output row receiving filter row ii
            if (o >= 0 && o < STRIP) {
                const int s = ((unsigned)o) % 7;  // compile-time under full unroll
                #pragma unroll
                for (int q = 0; q < 4; ++q) {
                    #pragma unroll
                    for (int jj = 0; jj < 7; ++jj)
                        acc[s][q] += d[ii * 7 + jj] * v[q + jj + 1];
                }
            }
        }
        if (i >= 6) {
            const int o = i - 6;
            const int s = ((unsigned)o) % 7;
            f32x4 ov = {acc[s][0], acc[s][1], acc[s][2], acc[s][3]};
            __builtin_nontemporal_store(ov, (f32x4*)(op + (yb + o) * HW + 4 * lane));
            acc[s][0] = 0.f; acc[s][1] = 0.f; acc[s][2] = 0.f; acc[s][3] = 0.f;
        }
    }
}

extern "C" void kernel_launch(void* const* d_in, const int* in_sizes, int n_in,
                              void* d_out, int out_size, void* d_ws, size_t ws_size,
                              hipStream_t stream) {
    const float* x        = (const float*)d_in[0];
    const float* guidance = (const float*)d_in[1];
    const float* basis    = (const float*)d_in[2];
    const float* w1       = (const float*)d_in[3];
    const float* b1       = (const float*)d_in[4];
    const float* w2       = (const float*)d_in[5];
    const float* b2       = (const float*)d_in[6];
    float* out = (float*)d_out;
    float* ws  = (float*)d_ws;

    float* partial = ws;                  // 4096
    float* wt      = ws + 4096;           // 32
    float* dynF    = ws + 4096 + 32;      // 50176

    mean1_kernel<<<4096, 256, 0, stream>>>(guidance, partial);
    mlp_kernel<<<1, 256, 0, stream>>>(partial, w1, b1, w2, b2, wt);
    dyn_kernel<<<(BATCH * CH * 49 + 255) / 256, 256, 0, stream>>>(wt, basis, dynF);
    conv_kernel<<<dim3(BATCH * CH, HW / (4 * STRIP)), 256, 0, stream>>>(x, dynF, out);
}

// Round 13
// 203.788 us; speedup vs baseline: 2.3326x; 2.3326x over previous
//
#include <hip/hip_runtime.h>

#define HW 256
#define HWMASK 255
#define CH 128
#define BATCH 8
#define NK 4
#define TSY 16
#define NQROW 66                 // quads per LDS row: cols -4..259 wrapped
#define NROWS 22                 // 16 + 3 halo each side
#define NSTAGE (NROWS * NQROW)   // 1452 quads = 23232 B per buffer
#define NT 8                     // tiles per block (128 rows = half plane)

typedef float f32x4 __attribute__((ext_vector_type(4)));

__device__ __forceinline__ void load_lds16(const void* g, void* l) {
    __builtin_amdgcn_global_load_lds((const __attribute__((address_space(1))) void*)g,
                                     (__attribute__((address_space(3))) void*)l, 16, 0, 0);
}

// stage one 22-row window starting at absolute row ystart (= tile_y0 - 3)
__device__ __forceinline__ void stage_tile(const float* xp, float4* buf, int ystart, int tid) {
    #pragma unroll
    for (int k = 0; k < 6; ++k) {
        int e = (k < 5) ? k * 256 + tid : (NSTAGE - 256) + tid;   // tail overlaps: dup-safe
        int r = e / NQROW, q = e - r * NQROW;
        int gy = (ystart + r) & HWMASK;
        int gx = (4 * q - 4) & HWMASK;
        load_lds16(xp + gy * HW + gx, &buf[e]);
    }
}

// ---------------- Kernel A1: partial sums of guidance ----------------
__global__ __launch_bounds__(256) void mean1_kernel(const float* __restrict__ guid,
                                                    float* __restrict__ partial) {
    int blk = blockIdx.x;
    const float4* p = (const float4*)(guid + (size_t)blk * 16384);
    float s = 0.f;
    for (int i = threadIdx.x; i < 4096; i += 256) {
        float4 v = p[i];
        s += (v.x + v.y) + (v.z + v.w);
    }
    for (int off = 32; off; off >>= 1) s += __shfl_down(s, off, 64);
    __shared__ float red[4];
    if ((threadIdx.x & 63) == 0) red[threadIdx.x >> 6] = s;
    __syncthreads();
    if (threadIdx.x == 0) partial[blk] = (red[0] + red[1]) + (red[2] + red[3]);
}

// ---------------- Kernel B: finalize means + MLP + softmax ----------------
__global__ __launch_bounds__(256) void mlp_kernel(const float* __restrict__ partial,
                                                  const float* __restrict__ w1,
                                                  const float* __restrict__ b1,
                                                  const float* __restrict__ w2,
                                                  const float* __restrict__ b2,
                                                  float* __restrict__ wt) {
    __shared__ float gs[BATCH * CH];
    __shared__ float h1[BATCH * 32];
    __shared__ float lg[BATCH * NK];
    int t = threadIdx.x;
    for (int i = t; i < BATCH * CH; i += 256) {
        float4 v = *(const float4*)(partial + i * 4);
        gs[i] = ((v.x + v.y) + (v.z + v.w)) * (1.0f / 65536.0f);
    }
    __syncthreads();
    {
        int b = t >> 5, j = t & 31;
        float acc = b1[j];
        #pragma unroll 4
        for (int c = 0; c < CH; ++c) acc += gs[b * CH + c] * w1[j * CH + c];
        h1[b * 32 + j] = fmaxf(acc, 0.f);
    }
    __syncthreads();
    if (t < BATCH * NK) {
        int b = t >> 2, k = t & 3;
        float acc = b2[k];
        #pragma unroll
        for (int j = 0; j < 32; ++j) acc += h1[b * 32 + j] * w2[k * 32 + j];
        lg[b * NK + k] = acc;
    }
    __syncthreads();
    if (t < BATCH) {
        int b = t;
        float m = lg[b * 4];
        for (int k = 1; k < 4; ++k) m = fmaxf(m, lg[b * 4 + k]);
        float e[4], s = 0.f;
        for (int k = 0; k < 4; ++k) { e[k] = expf(lg[b * 4 + k] - m); s += e[k]; }
        float inv = 1.0f / s;
        for (int k = 0; k < 4; ++k) wt[b * 4 + k] = e[k] * inv;
    }
}

// ---------------- Kernel C: dyn = blend of basis filters, stored FLIPPED ----------------
__global__ __launch_bounds__(256) void dyn_kernel(const float* __restrict__ wt,
                                                  const float* __restrict__ basis,
                                                  float* __restrict__ dynF) {
    int idx = blockIdx.x * 256 + threadIdx.x;
    if (idx >= BATCH * CH * 49) return;
    int ij = idx % 49;
    int bc = idx / 49;
    int c = bc % CH;
    int b = bc / CH;
    float acc = 0.f;
    #pragma unroll
    for (int k = 0; k < NK; ++k)
        acc += wt[b * NK + k] * basis[(k * CH + c) * 49 + ij];
    dynF[bc * 49 + (48 - ij)] = acc;
}

// ---------------- Kernel D: circular depthwise 7x7 conv ----------------
// Persistent over NT y-tiles. TRIPLE-buffered LDS with 2-tile-ahead
// global_load_lds prefetch: each tile's loads get ~2 compute rounds to land,
// so the end-of-round vmcnt never exposes HBM queue-drain latency.
__global__ __launch_bounds__(256) void conv_kernel(const float* __restrict__ x,
                                                   const float* __restrict__ dynF,
                                                   float* __restrict__ out) {
    int bc = blockIdx.x;                  // 0..1023
    int ybase = blockIdx.y * (NT * TSY);  // 0 or 128
    __shared__ float4 lds4[3][NSTAGE];    // 69.7 KB -> 2 blocks/CU
    const float* xp = x + (size_t)bc * (HW * HW);
    float* op = out + (size_t)bc * (HW * HW);
    int tid = threadIdx.x;

    // filter taps: block-uniform address -> scalar loads into SGPRs
    const float* df = dynF + bc * 49;
    float d[49];
    #pragma unroll
    for (int i = 0; i < 49; ++i) d[i] = df[i];

    // prologue: stage tiles 0 and 1
    stage_tile(xp, lds4[0], ybase - 3, tid);
    stage_tile(xp, lds4[1], ybase + TSY - 3, tid);
    asm volatile("s_waitcnt vmcnt(6)" ::: "memory");   // tile 0 ready (tile 1 in flight)
    __builtin_amdgcn_s_barrier();

    int tx = tid & 63, ty = tid >> 6;
    int ly0 = 4 * ty;
    int cur = 0, pre = 2;

    #pragma unroll 1
    for (int t = 0; t < NT; ++t) {
        // issue prefetch of tile t+2 (overwrites buffer last read at tile t-1;
        // end-of-(t-1) barrier ordered those reads before these writes)
        if (t + 2 < NT)
            stage_tile(xp, lds4[pre], ybase + (t + 2) * TSY - 3, tid);

        // compute tile t
        int y0 = ybase + t * TSY;
        const float4* LB = lds4[cur];
        float acc[4][4] = {};
        #pragma unroll
        for (int rr = 0; rr < 10; ++rr) {
            const float4* rp = &LB[(ly0 + rr) * NQROW + tx];
            float4 A = rp[0], B = rp[1], C = rp[2];
            float v[12] = {A.x, A.y, A.z, A.w, B.x, B.y, B.z, B.w, C.x, C.y, C.z, C.w};
            #pragma unroll
            for (int rq = 0; rq < 4; ++rq) {
                int ii = rr - rq;
                if (ii >= 0 && ii <= 6) {
                    #pragma unroll
                    for (int q = 0; q < 4; ++q) {
                        #pragma unroll
                        for (int jj = 0; jj < 7; ++jj)
                            acc[rq][q] += d[ii * 7 + jj] * v[q + jj + 1];
                    }
                }
            }
        }
        #pragma unroll
        for (int rq = 0; rq < 4; ++rq) {
            f32x4 o = {acc[rq][0], acc[rq][1], acc[rq][2], acc[rq][3]};
            __builtin_nontemporal_store(o, (f32x4*)(op + (y0 + ly0 + rq) * HW + 4 * tx));
        }

        // wait: tile t+1's loads done. In-order vmcnt; newer ops =
        // stage(t+2) [6 if issued] + our 4 stores.
        if (t < NT - 1) {
            if (t + 2 < NT) asm volatile("s_waitcnt vmcnt(10)" ::: "memory");
            else            asm volatile("s_waitcnt vmcnt(8)"  ::: "memory");
            __builtin_amdgcn_s_barrier();
        }
        cur = (cur == 2) ? 0 : cur + 1;
        pre = (pre == 2) ? 0 : pre + 1;
    }
}

extern "C" void kernel_launch(void* const* d_in, const int* in_sizes, int n_in,
                              void* d_out, int out_size, void* d_ws, size_t ws_size,
                              hipStream_t stream) {
    const float* x        = (const float*)d_in[0];
    const float* guidance = (const float*)d_in[1];
    const float* basis    = (const float*)d_in[2];
    const float* w1       = (const float*)d_in[3];
    const float* b1       = (const float*)d_in[4];
    const float* w2       = (const float*)d_in[5];
    const float* b2       = (const float*)d_in[6];
    float* out = (float*)d_out;
    float* ws  = (float*)d_ws;

    float* partial = ws;                  // 4096
    float* wt      = ws + 4096;           // 32
    float* dynF    = ws + 4096 + 32;      // 50176

    mean1_kernel<<<4096, 256, 0, stream>>>(guidance, partial);
    mlp_kernel<<<1, 256, 0, stream>>>(partial, w1, b1, w2, b2, wt);
    dyn_kernel<<<(BATCH * CH * 49 + 255) / 256, 256, 0, stream>>>(wt, basis, dynF);
    conv_kernel<<<dim3(BATCH * CH, HW / (NT * TSY)), 256, 0, stream>>>(x, dynF, out);
}

// Round 14
// 199.402 us; speedup vs baseline: 2.3839x; 1.0220x over previous
//
#include <hip/hip_runtime.h>

#define HW 256
#define HWMASK 255
#define CH 128
#define BATCH 8
#define NK 4
#define TSY 16
#define QR 66                    // float4 quads per row: cols -4..259 wrapped
#define RRING 40                 // ring rows: 22 live + 16 staged + 2 slack
#define NT 8                     // tiles per block (128 rows = half plane)

typedef float f32x4 __attribute__((ext_vector_type(4)));

__device__ __forceinline__ void load_lds16(const void* g, void* l) {
    __builtin_amdgcn_global_load_lds((const __attribute__((address_space(1))) void*)g,
                                     (__attribute__((address_space(3))) void*)l, 16, 0, 0);
}

// stage rows [row0, row0+nrows) into ring slots (row mod 40) — caller guarantees
// the slot range doesn't wrap mod 40, so LDS destinations are lane-linear.
__device__ __forceinline__ void stage_rows(const float* xp, float4* ring,
                                           int row0, int nrows, int tid) {
    int slot0 = ((row0 % RRING) + RRING) % RRING;
    int total = nrows * QR;
    float4* base = ring + slot0 * QR;
    #pragma unroll 1
    for (int off = 0; off < total; off += 256) {
        int e = off + tid;
        if (e < total) {
            int ro = e / QR, q = e - ro * QR;
            int gy = (row0 + ro) & HWMASK;
            int gx = (4 * q - 4) & HWMASK;
            load_lds16(xp + gy * HW + gx, &base[e]);
        }
    }
}

// ---------------- Kernel A1: partial sums of guidance ----------------
__global__ __launch_bounds__(256) void mean1_kernel(const float* __restrict__ guid,
                                                    float* __restrict__ partial) {
    int blk = blockIdx.x;
    const float4* p = (const float4*)(guid + (size_t)blk * 16384);
    float s = 0.f;
    for (int i = threadIdx.x; i < 4096; i += 256) {
        float4 v = p[i];
        s += (v.x + v.y) + (v.z + v.w);
    }
    for (int off = 32; off; off >>= 1) s += __shfl_down(s, off, 64);
    __shared__ float red[4];
    if ((threadIdx.x & 63) == 0) red[threadIdx.x >> 6] = s;
    __syncthreads();
    if (threadIdx.x == 0) partial[blk] = (red[0] + red[1]) + (red[2] + red[3]);
}

// ---------------- Kernel B: finalize means + MLP + softmax ----------------
__global__ __launch_bounds__(256) void mlp_kernel(const float* __restrict__ partial,
                                                  const float* __restrict__ w1,
                                                  const float* __restrict__ b1,
                                                  const float* __restrict__ w2,
                                                  const float* __restrict__ b2,
                                                  float* __restrict__ wt) {
    __shared__ float gs[BATCH * CH];
    __shared__ float h1[BATCH * 32];
    __shared__ float lg[BATCH * NK];
    int t = threadIdx.x;
    for (int i = t; i < BATCH * CH; i += 256) {
        float4 v = *(const float4*)(partial + i * 4);
        gs[i] = ((v.x + v.y) + (v.z + v.w)) * (1.0f / 65536.0f);
    }
    __syncthreads();
    {
        int b = t >> 5, j = t & 31;
        float acc = b1[j];
        #pragma unroll 4
        for (int c = 0; c < CH; ++c) acc += gs[b * CH + c] * w1[j * CH + c];
        h1[b * 32 + j] = fmaxf(acc, 0.f);
    }
    __syncthreads();
    if (t < BATCH * NK) {
        int b = t >> 2, k = t & 3;
        float acc = b2[k];
        #pragma unroll
        for (int j = 0; j < 32; ++j) acc += h1[b * 32 + j] * w2[k * 32 + j];
        lg[b * NK + k] = acc;
    }
    __syncthreads();
    if (t < BATCH) {
        int b = t;
        float m = lg[b * 4];
        for (int k = 1; k < 4; ++k) m = fmaxf(m, lg[b * 4 + k]);
        float e[4], s = 0.f;
        for (int k = 0; k < 4; ++k) { e[k] = expf(lg[b * 4 + k] - m); s += e[k]; }
        float inv = 1.0f / s;
        for (int k = 0; k < 4; ++k) wt[b * 4 + k] = e[k] * inv;
    }
}

// ---------------- Kernel C: dyn = blend of basis filters, stored FLIPPED ----------------
__global__ __launch_bounds__(256) void dyn_kernel(const float* __restrict__ wt,
                                                  const float* __restrict__ basis,
                                                  float* __restrict__ dynF) {
    int idx = blockIdx.x * 256 + threadIdx.x;
    if (idx >= BATCH * CH * 49) return;
    int ij = idx % 49;
    int bc = idx / 49;
    int c = bc % CH;
    int b = bc / CH;
    float acc = 0.f;
    #pragma unroll
    for (int k = 0; k < NK; ++k)
        acc += wt[b * NK + k] * basis[(k * CH + c) * 49 + ij];
    dynF[bc * 49 + (48 - ij)] = acc;
}

// ---------------- Kernel D: circular depthwise 7x7 conv, ring-buffer staging ----
// 40-row LDS ring (42.2 KB -> 3 blocks/CU). Per round: global_load_lds the 16 NEW
// rows only (halo re-staging eliminated), compute 16 rows from the ring, store,
// vmcnt(4) + barrier. Slot disjointness: stage rows == window rows + {22..37} mod 40.
__global__ __launch_bounds__(256) void conv_kernel(const float* __restrict__ x,
                                                   const float* __restrict__ dynF,
                                                   float* __restrict__ out) {
    int bc = blockIdx.x;                  // 0..1023
    int ybase = blockIdx.y * (NT * TSY);  // 0 or 128
    __shared__ float4 ring[RRING * QR];   // 42240 B
    const float* xp = x + (size_t)bc * (HW * HW);
    float* op = out + (size_t)bc * (HW * HW);
    int tid = threadIdx.x;

    // filter taps: block-uniform address -> scalar loads into SGPRs
    const float* df = dynF + bc * 49;
    float d[49];
    #pragma unroll
    for (int i = 0; i < 49; ++i) d[i] = df[i];

    // prologue: stage window(0) = rows [ybase-3, ybase+18] (2 pieces if slot-wrap)
    {
        int row0 = ybase - 3;
        int s0 = ((row0 % RRING) + RRING) % RRING;
        int p1 = min(22, RRING - s0);
        stage_rows(xp, ring, row0, p1, tid);
        if (p1 < 22) stage_rows(xp, ring, row0 + p1, 22 - p1, tid);
    }
    asm volatile("s_waitcnt vmcnt(0)" ::: "memory");
    __builtin_amdgcn_s_barrier();

    int tx = tid & 63, ty = tid >> 6;
    int ly0 = 4 * ty;

    #pragma unroll 1
    for (int t = 0; t < NT; ++t) {
        // issue stage of the next 16 rows [ybase+16t+19, +34] (slots disjoint
        // from window(t); end-of-(t-1) barrier ordered prior reads before this)
        if (t + 1 < NT) {
            int rb = ybase + 16 * t + 19;
            int s0 = rb % RRING;
            int p1 = min(16, RRING - s0);
            stage_rows(xp, ring, rb, p1, tid);
            if (p1 < 16) stage_rows(xp, ring, rb + p1, 16 - p1, tid);
        }

        // compute tile t from ring window [ybase+16t-3, ybase+16t+18]
        int y0 = ybase + 16 * t + ly0;
        float acc[4][4] = {};
        #pragma unroll
        for (int rr = 0; rr < 10; ++rr) {
            int row = y0 + rr - 3;
            int slot = ((row % RRING) + RRING) % RRING;
            const float4* rp = &ring[slot * QR + tx];
            float4 A = rp[0], B = rp[1], C = rp[2];
            float v[12] = {A.x, A.y, A.z, A.w, B.x, B.y, B.z, B.w, C.x, C.y, C.z, C.w};
            #pragma unroll
            for (int rq = 0; rq < 4; ++rq) {
                int ii = rr - rq;
                if (ii >= 0 && ii <= 6) {
                    #pragma unroll
                    for (int q = 0; q < 4; ++q) {
                        #pragma unroll
                        for (int jj = 0; jj < 7; ++jj)
                            acc[rq][q] += d[ii * 7 + jj] * v[q + jj + 1];
                    }
                }
            }
        }
        #pragma unroll
        for (int rq = 0; rq < 4; ++rq) {
            f32x4 o = {acc[rq][0], acc[rq][1], acc[rq][2], acc[rq][3]};
            __builtin_nontemporal_store(o, (f32x4*)(op + (y0 + rq) * HW + 4 * tx));
        }

        // drain this round's stage loads (in-order: the 4 newest = our stores)
        if (t + 1 < NT) {
            asm volatile("s_waitcnt vmcnt(4)" ::: "memory");
            __builtin_amdgcn_s_barrier();
        }
    }
}

extern "C" void kernel_launch(void* const* d_in, const int* in_sizes, int n_in,
                              void* d_out, int out_size, void* d_ws, size_t ws_size,
                              hipStream_t stream) {
    const float* x        = (const float*)d_in[0];
    const float* guidance = (const float*)d_in[1];
    const float* basis    = (const float*)d_in[2];
    const float* w1       = (const float*)d_in[3];
    const float* b1       = (const float*)d_in[4];
    const float* w2       = (const float*)d_in[5];
    const float* b2       = (const float*)d_in[6];
    float* out = (float*)d_out;
    float* ws  = (float*)d_ws;

    float* partial = ws;                  // 4096
    float* wt      = ws + 4096;           // 32
    float* dynF    = ws + 4096 + 32;      // 50176

    mean1_kernel<<<4096, 256, 0, stream>>>(guidance, partial);
    mlp_kernel<<<1, 256, 0, stream>>>(partial, w1, b1, w2, b2, wt);
    dyn_kernel<<<(BATCH * CH * 49 + 255) / 256, 256, 0, stream>>>(wt, basis, dynF);
    conv_kernel<<<dim3(BATCH * CH, HW / (NT * TSY)), 256, 0, stream>>>(x, dynF, out);
}

// Round 15
// 187.408 us; speedup vs baseline: 2.5365x; 1.0640x over previous
//
#include <hip/hip_runtime.h>

#define HW 256
#define HWMASK 255
#define CH 128
#define BATCH 8
#define NK 4
#define TSY 16
#define NQROW 66                 // quads per LDS row: cols -4..259 wrapped
#define NROWS 22                 // 16 + 3 halo each side
#define NSTAGE (NROWS * NQROW)   // 1452 quads = 23232 B per buffer
#define NT 8                     // tiles per block (128 rows = half plane)

typedef float f32x4 __attribute__((ext_vector_type(4)));

// ---------------- Kernel A1: partial sums of guidance ----------------
__global__ __launch_bounds__(256) void mean1_kernel(const float* __restrict__ guid,
                                                    float* __restrict__ partial) {
    int blk = blockIdx.x;
    const float4* p = (const float4*)(guid + (size_t)blk * 16384);
    float s = 0.f;
    for (int i = threadIdx.x; i < 4096; i += 256) {
        float4 v = p[i];
        s += (v.x + v.y) + (v.z + v.w);
    }
    for (int off = 32; off; off >>= 1) s += __shfl_down(s, off, 64);
    __shared__ float red[4];
    if ((threadIdx.x & 63) == 0) red[threadIdx.x >> 6] = s;
    __syncthreads();
    if (threadIdx.x == 0) partial[blk] = (red[0] + red[1]) + (red[2] + red[3]);
}

// ---------------- Kernel B: finalize means + MLP + softmax ----------------
__global__ __launch_bounds__(256) void mlp_kernel(const float* __restrict__ partial,
                                                  const float* __restrict__ w1,
                                                  const float* __restrict__ b1,
                                                  const float* __restrict__ w2,
                                                  const float* __restrict__ b2,
                                                  float* __restrict__ wt) {
    __shared__ float gs[BATCH * CH];
    __shared__ float h1[BATCH * 32];
    __shared__ float lg[BATCH * NK];
    int t = threadIdx.x;
    for (int i = t; i < BATCH * CH; i += 256) {
        float4 v = *(const float4*)(partial + i * 4);
        gs[i] = ((v.x + v.y) + (v.z + v.w)) * (1.0f / 65536.0f);
    }
    __syncthreads();
    {
        int b = t >> 5, j = t & 31;
        float acc = b1[j];
        #pragma unroll 4
        for (int c = 0; c < CH; ++c) acc += gs[b * CH + c] * w1[j * CH + c];
        h1[b * 32 + j] = fmaxf(acc, 0.f);
    }
    __syncthreads();
    if (t < BATCH * NK) {
        int b = t >> 2, k = t & 3;
        float acc = b2[k];
        #pragma unroll
        for (int j = 0; j < 32; ++j) acc += h1[b * 32 + j] * w2[k * 32 + j];
        lg[b * NK + k] = acc;
    }
    __syncthreads();
    if (t < BATCH) {
        int b = t;
        float m = lg[b * 4];
        for (int k = 1; k < 4; ++k) m = fmaxf(m, lg[b * 4 + k]);
        float e[4], s = 0.f;
        for (int k = 0; k < 4; ++k) { e[k] = expf(lg[b * 4 + k] - m); s += e[k]; }
        float inv = 1.0f / s;
        for (int k = 0; k < 4; ++k) wt[b * 4 + k] = e[k] * inv;
    }
}

// ---------------- Kernel C: dyn = blend of basis filters, stored FLIPPED ----------------
__global__ __launch_bounds__(256) void dyn_kernel(const float* __restrict__ wt,
                                                  const float* __restrict__ basis,
                                                  float* __restrict__ dynF) {
    int idx = blockIdx.x * 256 + threadIdx.x;
    if (idx >= BATCH * CH * 49) return;
    int ij = idx % 49;
    int bc = idx / 49;
    int c = bc % CH;
    int b = bc / CH;
    float acc = 0.f;
    #pragma unroll
    for (int k = 0; k < NK; ++k)
        acc += wt[b * NK + k] * basis[(k * CH + c) * 49 + ij];
    dynF[bc * 49 + (48 - ij)] = acc;
}

// ---------------- Kernel D: circular depthwise 7x7 conv ----------------
// R6 structure with T14 reg-staging: global->reg loads issued at loop top
// (land during compute, no LDS-side DMA contention), ds_write burst + single
// raw barrier per round (no vmcnt(0) store drain).
__global__ __launch_bounds__(256) void conv_kernel(const float* __restrict__ x,
                                                   const float* __restrict__ dynF,
                                                   float* __restrict__ out) {
    int bc = blockIdx.x;                  // 0..1023
    int ybase = blockIdx.y * (NT * TSY);  // 0 or 128
    __shared__ float4 lds4[2][NSTAGE];
    const float* xp = x + (size_t)bc * (HW * HW);
    float* op = out + (size_t)bc * (HW * HW);
    int tid = threadIdx.x;

    // filter taps: block-uniform address -> scalar loads into SGPRs
    const float* df = dynF + bc * 49;
    float d[49];
    #pragma unroll
    for (int i = 0; i < 49; ++i) d[i] = df[i];

    // per-chunk staging geometry (fixed per thread)
    int e0[6], rr0[6], gxq[6];
    #pragma unroll
    for (int k = 0; k < 6; ++k) {
        int e = (k < 5) ? k * 256 + tid : (NSTAGE - 256) + tid;  // tail overlap: dup-safe
        int r = e / NQROW, q = e - r * NQROW;
        e0[k] = e; rr0[k] = r; gxq[k] = (4 * q - 4) & HWMASK;
    }

    float4 pf0, pf1, pf2, pf3, pf4, pf5;
    #define LOADS(ys)                                                            \
        { int gy;                                                                \
          gy = ((ys) + rr0[0]) & HWMASK; pf0 = *(const float4*)(xp + gy * HW + gxq[0]); \
          gy = ((ys) + rr0[1]) & HWMASK; pf1 = *(const float4*)(xp + gy * HW + gxq[1]); \
          gy = ((ys) + rr0[2]) & HWMASK; pf2 = *(const float4*)(xp + gy * HW + gxq[2]); \
          gy = ((ys) + rr0[3]) & HWMASK; pf3 = *(const float4*)(xp + gy * HW + gxq[3]); \
          gy = ((ys) + rr0[4]) & HWMASK; pf4 = *(const float4*)(xp + gy * HW + gxq[4]); \
          gy = ((ys) + rr0[5]) & HWMASK; pf5 = *(const float4*)(xp + gy * HW + gxq[5]); }
    #define WRITES(buf)                                                          \
        { (buf)[e0[0]] = pf0; (buf)[e0[1]] = pf1; (buf)[e0[2]] = pf2;            \
          (buf)[e0[3]] = pf3; (buf)[e0[4]] = pf4; (buf)[e0[5]] = pf5; }

    // prologue: stage tile 0 into buf 0
    LOADS(ybase - 3);
    WRITES(lds4[0]);
    __syncthreads();

    int tx = tid & 63, ty = tid >> 6;
    int ly0 = 4 * ty;

    #pragma unroll 1
    for (int t = 0; t < NT; ++t) {
        // issue next tile's global loads into registers (land during compute)
        if (t + 1 < NT) LOADS(ybase + (t + 1) * TSY - 3);

        // compute current tile
        int y0 = ybase + t * TSY;
        const float4* LB = lds4[t & 1];
        float acc[4][4] = {};
        #pragma unroll
        for (int rr = 0; rr < 10; ++rr) {
            const float4* rp = &LB[(ly0 + rr) * NQROW + tx];
            float4 A = rp[0], B = rp[1], C = rp[2];
            float v[12] = {A.x, A.y, A.z, A.w, B.x, B.y, B.z, B.w, C.x, C.y, C.z, C.w};
            #pragma unroll
            for (int rq = 0; rq < 4; ++rq) {
                int ii = rr - rq;
                if (ii >= 0 && ii <= 6) {
                    #pragma unroll
                    for (int q = 0; q < 4; ++q) {
                        #pragma unroll
                        for (int jj = 0; jj < 7; ++jj)
                            acc[rq][q] += d[ii * 7 + jj] * v[q + jj + 1];
                    }
                }
            }
        }
        #pragma unroll
        for (int rq = 0; rq < 4; ++rq) {
            f32x4 o = {acc[rq][0], acc[rq][1], acc[rq][2], acc[rq][3]};
            __builtin_nontemporal_store(o, (f32x4*)(op + (y0 + ly0 + rq) * HW + 4 * tx));
        }

        // commit staged tile to the other buffer; one barrier per round
        if (t + 1 < NT) {
            WRITES(lds4[(t + 1) & 1]);
            asm volatile("s_waitcnt lgkmcnt(0)" ::: "memory");
            __builtin_amdgcn_s_barrier();
        }
    }
    #undef LOADS
    #undef WRITES
}

extern "C" void kernel_launch(void* const* d_in, const int* in_sizes, int n_in,
                              void* d_out, int out_size, void* d_ws, size_t ws_size,
                              hipStream_t stream) {
    const float* x        = (const float*)d_in[0];
    const float* guidance = (const float*)d_in[1];
    const float* basis    = (const float*)d_in[2];
    const float* w1       = (const float*)d_in[3];
    const float* b1       = (const float*)d_in[4];
    const float* w2       = (const float*)d_in[5];
    const float* b2       = (const float*)d_in[6];
    float* out = (float*)d_out;
    float* ws  = (float*)d_ws;

    float* partial = ws;                  // 4096
    float* wt      = ws + 4096;           // 32
    float* dynF    = ws + 4096 + 32;      // 50176

    mean1_kernel<<<4096, 256, 0, stream>>>(guidance, partial);
    mlp_kernel<<<1, 256, 0, stream>>>(partial, w1, b1, w2, b2, wt);
    dyn_kernel<<<(BATCH * CH * 49 + 255) / 256, 256, 0, stream>>>(wt, basis, dynF);
    conv_kernel<<<dim3(BATCH * CH, HW / (NT * TSY)), 256, 0, stream>>>(x, dynF, out);
}